// Round 8
// baseline (3555.691 us; speedup 1.0000x reference)
//
#include <hip/hip_runtime.h>

// Problem dims
#define B_   2048
#define D_   256
#define K_   20
#define UD_  512
#define E_   64
#define H_   256
#define HID_ 512

typedef __attribute__((ext_vector_type(8))) short bf8;    // 8 x bf16 MFMA A/B frag
typedef __attribute__((ext_vector_type(4))) short s4;     // 4 x bf16 (8B)
typedef __attribute__((ext_vector_type(4))) float f32x4;  // MFMA C/D frag
typedef __attribute__((ext_vector_type(4))) float f4;

#define MFMA16(a,b,c) __builtin_amdgcn_mfma_f32_16x16x32_bf16(a, b, c, 0, 0, 0)

// Device-coherent (L2-point) accesses via sc1 -> no cache flush/inv.
#define GLD(dst, p)  asm volatile("global_load_dwordx4 %0, %1, off sc1" : "=v"(dst) : "v"(p))
#define GST2(p, v)   asm volatile("global_store_dwordx2 %0, %1, off sc1" :: "v"(p), "v"(v) : "memory")
#define GSTD(p, v)   asm volatile("global_store_dword %0, %1, off sc1" :: "v"(p), "v"(v) : "memory")
#define GLDD(dst, p) asm volatile("global_load_dword %0, %1, off sc1\n\ts_waitcnt vmcnt(0)" : "=v"(dst) : "v"(p) : "memory")

__device__ __forceinline__ unsigned short f2bf(float x) {
  unsigned u = __float_as_uint(x);
  u += 0x7fffu + ((u >> 16) & 1u);   // RNE
  return (unsigned short)(u >> 16);
}
__device__ __forceinline__ float bfu(unsigned short x) {
  return __uint_as_float(((unsigned)x) << 16);
}
__device__ __forceinline__ float sigf(float x) {
  return __builtin_amdgcn_rcpf(1.0f + __expf(-x));
}
__device__ __forceinline__ float tanhf_(float x) {
  return 1.0f - 2.0f * __builtin_amdgcn_rcpf(__expf(2.0f * x) + 1.0f);
}

// ---------------------------------------------------------------------------
// Pack a [N,K] row-major f32 weight into MFMA B-fragment order (bf16).
// ---------------------------------------------------------------------------
__global__ __launch_bounds__(256) void pack_w(const float* __restrict__ W,
    unsigned short* __restrict__ dst, int NT, int KTsrc, int KTtot, int kt0,
    int ldw, int Nsrc)
{
  int idx = blockIdx.x * 256 + threadIdx.x;
  int total = NT * KTsrc * 64;
  if (idx >= total) return;
  int l  = idx & 63;
  int fk = idx >> 6;
  int kt = fk % KTsrc;
  int nt = fk / KTsrc;
  int n = nt * 16 + (l & 15);
  int k = kt * 32 + ((l >> 4) * 8);
  bf8 o;
#pragma unroll
  for (int j = 0; j < 8; ++j)
    o[j] = (n < Nsrc) ? (short)f2bf(W[(size_t)n * ldw + k + j]) : (short)0;
  *(bf8*)(dst + (((size_t)(nt * KTtot + kt0 + kt)) * 64 + l) * 8) = o;
}

// f32 -> bf16 row-major convert (8 elems / thread)
__global__ __launch_bounds__(256) void cvt_bf(const float* __restrict__ src,
    unsigned short* __restrict__ dst, int n8)
{
  int i = blockIdx.x * 256 + threadIdx.x;
  if (i >= n8) return;
  const f4* s = (const f4*)(src + (size_t)i * 8);
  f4 v0 = s[0], v1 = s[1];
  bf8 o;
#pragma unroll
  for (int j = 0; j < 4; ++j) { o[j] = (short)f2bf(v0[j]); o[4 + j] = (short)f2bf(v1[j]); }
  *(bf8*)(dst + (size_t)i * 8) = o;
}

// ---------------------------------------------------------------------------
// Generic C = A @ W^T + bias (pre-pass FiLM GEMMs).
// ---------------------------------------------------------------------------
template<bool OUTBF>
__global__ __launch_bounds__(256) void gemm_bt(
    const unsigned short* __restrict__ A, int lda, int aoff,
    const unsigned short* __restrict__ Bp, int KT,
    void* __restrict__ Cptr, int ldc, int coff,
    const float* __restrict__ bias)
{
  int tid = threadIdx.x;
  int l = tid & 63, w = tid >> 6;
  int wr = w >> 1, wc = w & 1;
  int r0 = blockIdx.y * 64 + wr * 32;
  int n0 = blockIdx.x * 64 + wc * 32;
  int lr = l & 15, lk = (l >> 4) * 8;
  f32x4 acc[2][2] = {};
  const unsigned short* a0p = A + (size_t)(r0 + lr) * lda + aoff + lk;
  const unsigned short* a1p = A + (size_t)(r0 + 16 + lr) * lda + aoff + lk;
  int ntb = n0 >> 4;
  for (int kt = 0; kt < KT; ++kt) {
    bf8 a0 = *(const bf8*)(a0p + kt * 32);
    bf8 a1 = *(const bf8*)(a1p + kt * 32);
    bf8 b0 = *(const bf8*)(Bp + (((size_t)(ntb + 0) * KT + kt) * 64 + l) * 8);
    bf8 b1 = *(const bf8*)(Bp + (((size_t)(ntb + 1) * KT + kt) * 64 + l) * 8);
    acc[0][0] = MFMA16(a0, b0, acc[0][0]);
    acc[0][1] = MFMA16(a0, b1, acc[0][1]);
    acc[1][0] = MFMA16(a1, b0, acc[1][0]);
    acc[1][1] = MFMA16(a1, b1, acc[1][1]);
  }
#pragma unroll
  for (int mi = 0; mi < 2; ++mi)
#pragma unroll
  for (int nj = 0; nj < 2; ++nj)
#pragma unroll
  for (int r = 0; r < 4; ++r) {
    int row = r0 + mi * 16 + (l >> 4) * 4 + r;
    int n = n0 + nj * 16 + lr;
    float v = acc[mi][nj][r] + bias[n];
    if (OUTBF) ((unsigned short*)Cptr)[(size_t)row * ldc + coff + n] = f2bf(v);
    else       ((float*)Cptr)[(size_t)row * ldc + coff + n] = v;
  }
}

// LayerNorm(512) + SiLU over Hgb [2048,1024].
__global__ __launch_bounds__(256) void ln_silu(
    const float* __restrict__ Hgb, unsigned short* __restrict__ Hsi,
    const float* __restrict__ gw, const float* __restrict__ gb,
    const float* __restrict__ bw, const float* __restrict__ bb)
{
  int tid = threadIdx.x;
  int l = tid & 63, w = tid >> 6;
  int gwv = blockIdx.x * 4 + w;
  int row = gwv >> 1, br = gwv & 1;
  const float* base = Hgb + (size_t)row * 1024 + br * 512 + l * 8;
  f4 v0 = *(const f4*)base;
  f4 v1 = *(const f4*)(base + 4);
  float s1 = 0.f, s2 = 0.f;
#pragma unroll
  for (int j = 0; j < 4; ++j) { s1 += v0[j] + v1[j]; s2 += v0[j] * v0[j] + v1[j] * v1[j]; }
  for (int m = 1; m < 64; m <<= 1) { s1 += __shfl_xor(s1, m, 64); s2 += __shfl_xor(s2, m, 64); }
  float mean = s1 * (1.0f / 512.0f);
  float var  = s2 * (1.0f / 512.0f) - mean * mean;
  float rstd = rsqrtf(var + 1e-5f);
  const float* W  = br ? bw : gw;
  const float* Bb = br ? bb : gb;
  bf8 o;
#pragma unroll
  for (int j = 0; j < 8; ++j) {
    float x = (j < 4) ? v0[j] : v1[j - 4];
    float y = (x - mean) * rstd * W[l * 8 + j] + Bb[l * 8 + j];
    o[j] = (short)f2bf(y * sigf(y));
  }
  *(bf8*)(Hsi + (size_t)row * 1024 + br * 512 + l * 8) = o;
}

// ---------------------------------------------------------------------------
// Persistent kernel, v6: split-flag pipeline.
// 16 groups (128 rows) x 16 members (16 h-cols); 512-thread blocks (8 waves),
// each wave one 16-row M-tile. Per phase:
//   L0[ph] -> store h0 -> publish h0-flag -> wait peers' h0-flags ->
//   issue next ha loads (fly under L1) -> L1[ph-1] -> store h1 -> publish
//   h1-flag -> head[ph-2] -> xa[ph+1] -> wait h1-flags -> issue next h1 loads.
// Loop unrolled x2 with swapped register sets (no rotates; every asm-load def
// is covered by a vmcnt before use). Mod-2 h buffers are safe: a member can
// only publish h0-flag(t) after its loads of h0(t-1) were consumed.
// ---------------------------------------------------------------------------
struct PParams {
  const unsigned short* embB;
  const unsigned short* gbB;
  const unsigned short* E0;
  const unsigned short* W0p;
  const unsigned short* W1p;
  const unsigned short* Whp;
  unsigned short* H0;
  unsigned short* H1;
  unsigned* flags;               // [2][16 groups][16 u32] (h0f, h1f)
  const float* bih0; const float* bhh0;
  const float* bih1; const float* bhh1;
  const float* headb;
  const int* X;
  float* out;
};

__device__ __forceinline__ bf8 mod_frag(const unsigned short* e,
                                        const unsigned short* gb)
{
  bf8 ev = *(const bf8*)e;
  bf8 gv = *(const bf8*)gb;
  bf8 bv = *(const bf8*)(gb + 64);
  bf8 o;
#pragma unroll
  for (int j = 0; j < 8; ++j) {
    float x = bfu((unsigned short)ev[j]) * (1.0f + bfu((unsigned short)gv[j]))
            + bfu((unsigned short)bv[j]);
    o[j] = (short)f2bf(x);
  }
  return o;
}

__device__ __forceinline__ void publish(unsigned* gf, int mem, unsigned target)
{
  asm volatile("s_waitcnt vmcnt(0)" ::: "memory");  // this wave's stores done
  __syncthreads();                                   // => all waves' stores done
  if (threadIdx.x == 0) GSTD(&gf[mem], target);
}
__device__ __forceinline__ void waitflags(unsigned* gf, int mem, unsigned target)
{
  int lane = threadIdx.x & 63;
  if (lane < 16 && lane != mem) {
    const unsigned* fp = &gf[lane];
    unsigned v;
    GLDD(v, fp);
    while (v < target) {
      __builtin_amdgcn_s_sleep(1);
      GLDD(v, fp);
    }
  }
}

__global__ __launch_bounds__(512, 2) void persistent(PParams P)
{
  __shared__ __align__(16) unsigned short ldsw[120 * 512];  // 120 KB weights
  __shared__ __align__(16) unsigned short tps[8][256];      // 4 KB transpose
  const int tid = threadIdx.x;
  const int l = tid & 63, w = tid >> 6;          // w in 0..7
  const int lr = l & 15, lk = (l >> 4) * 8;
  const int bx = blockIdx.x;
  const int gid = bx & 15;
  const int mem = bx >> 4;
  unsigned* h0f = P.flags + gid * 16;
  unsigned* h1f = P.flags + 256 + gid * 16;

  // ---- stage weight slices into LDS ----
  for (int f = w; f < 104; f += 8) {
    const unsigned short* src;
    if (f < 40) {
      int g = f / 10, kt = f - g * 10;
      src = P.W0p + (((size_t)((g * 16 + mem) * 10 + kt)) * 64 + l) * 8;
    } else {
      int f1 = f - 40; int g = f1 >> 4, kt = f1 & 15;
      src = P.W1p + (((size_t)((g * 16 + mem) * 16 + kt)) * 64 + l) * 8;
    }
    *(bf8*)(ldsw + (size_t)f * 512 + l * 8) = *(const bf8*)src;
  }
  for (int f = w; f < 16; f += 8)
    *(bf8*)(ldsw + (size_t)(104 + f) * 512 + l * 8) =
        *(const bf8*)(P.Whp + ((size_t)f * 64 + l) * 8);
  __syncthreads();

  const int r0 = gid * 128 + w * 16;             // this wave's 16 rows
  const int c  = mem * 16 + lr;
  const size_t HN = (size_t)B_ * H_;
  const int rowA = r0 + lr;
  const int row2 = l & 15, ch2 = (l >> 4) & 3;
  const size_t strow = (size_t)(r0 + row2) * H_ + mem * 16 + ch2 * 4;
  unsigned short* tb = &tps[w][0];

  const float bi0 = P.bih0[c]           + P.bhh0[c];
  const float bf0 = P.bih0[H_ + c]      + P.bhh0[H_ + c];
  const float bg0 = P.bih0[2 * H_ + c]  + P.bhh0[2 * H_ + c];
  const float bo0 = P.bih0[3 * H_ + c]  + P.bhh0[3 * H_ + c];
  const float bi1 = P.bih1[c]           + P.bhh1[c];
  const float bf1 = P.bih1[H_ + c]      + P.bhh1[H_ + c];
  const float bg1 = P.bih1[2 * H_ + c]  + P.bhh1[2 * H_ + c];
  const float bo1 = P.bih1[3 * H_ + c]  + P.bhh1[3 * H_ + c];
  const float hb0 = P.headb[lr];
  const float hb1 = (lr < 4) ? P.headb[16 + lr] : 0.f;

  float c0r[4] = {};
  float c1r[4] = {};
  float lq[4]  = {};

  // register sets (double-buffered across phases, swapped by role)
  bf8 z8 = {};
  bf8 haA[8], haB[8], h1A[8], h1B[8], xaA[2], xaB[2];
#pragma unroll
  for (int i = 0; i < 8; ++i) { haA[i] = z8; haB[i] = z8; h1A[i] = z8; h1B[i] = z8; }
#pragma unroll
  for (int kt = 0; kt < 2; ++kt)
    xaA[kt] = *(const bf8*)(P.E0 + (size_t)rowA * E_ + kt * 32 + lk);
  xaB[0] = z8; xaB[1] = z8;

  auto body = [&](int ph, bf8 (&haC)[8], bf8 (&haN)[8],
                          bf8 (&h1C)[8], bf8 (&h1N)[8],
                          bf8 (&xaC)[2], bf8 (&xaN)[2]) {
    unsigned short* h0wp = P.H0 + (size_t)(ph & 1) * HN;        // h0[ph]
    unsigned short* h1wp = P.H1 + (size_t)((ph + 1) & 1) * HN;  // h1[ph-1]

    // ---- L0[ph] ----
    if (ph < D_) {
      f32x4 acc[4] = {};
#pragma unroll
      for (int kt = 0; kt < 2; ++kt)
#pragma unroll
      for (int g = 0; g < 4; ++g) {
        bf8 b = *(const bf8*)(ldsw + (size_t)(g * 10 + kt) * 512 + l * 8);
        acc[g] = MFMA16(xaC[kt], b, acc[g]);
      }
      asm volatile("s_waitcnt vmcnt(8)" ::: "memory");   // haC resident
      __builtin_amdgcn_sched_barrier(0x100);             // only DS may cross
#pragma unroll
      for (int kt = 2; kt < 10; ++kt)
#pragma unroll
      for (int g = 0; g < 4; ++g) {
        bf8 b = *(const bf8*)(ldsw + (size_t)(g * 10 + kt) * 512 + l * 8);
        acc[g] = MFMA16(haC[kt - 2], b, acc[g]);
      }
#pragma unroll
      for (int r = 0; r < 4; ++r) {
        float iv = sigf(acc[0][r] + bi0);
        float fv = sigf(acc[1][r] + bf0);
        float gv = tanhf_(acc[2][r] + bg0);
        float ov = sigf(acc[3][r] + bo0);
        float cn = fv * c0r[r] + iv * gv;
        c0r[r] = cn;
        tb[((l >> 4) * 4 + r) * 16 + lr] = f2bf(ov * tanhf_(cn));
      }
      asm volatile("s_waitcnt lgkmcnt(0)" ::: "memory");
      __builtin_amdgcn_sched_barrier(0);
      bf8 hv0 = *(const bf8*)(tb + row2 * 16 + ch2 * 4);
      s4 sv = { hv0[0], hv0[1], hv0[2], hv0[3] };
      GST2(h0wp + strow, sv);
      publish(h0f, mem, (unsigned)(ph + 1));
      waitflags(h0f, mem, (unsigned)(ph + 1));
      // issue next-phase ha loads (h0[ph]); they fly under L1
      const unsigned short* pa = h0wp + (size_t)rowA * H_ + lk;
#pragma unroll
      for (int kt = 0; kt < 8; ++kt) GLD(haN[kt], pa + kt * 32);
    }
    if (ph >= D_) { asm volatile("s_waitcnt vmcnt(0)" ::: "memory"); }

    // ---- L1[ph-1] ----
    if (ph >= 1 && ph <= D_) {
      f32x4 acc[4] = {};
#pragma unroll
      for (int kt = 0; kt < 16; ++kt) {
        bf8 a = (kt < 8) ? haC[kt] : h1C[kt - 8];
#pragma unroll
        for (int g = 0; g < 4; ++g) {
          bf8 b = *(const bf8*)(ldsw + (size_t)(40 + g * 16 + kt) * 512 + l * 8);
          acc[g] = MFMA16(a, b, acc[g]);
        }
      }
#pragma unroll
      for (int r = 0; r < 4; ++r) {
        float iv = sigf(acc[0][r] + bi1);
        float fv = sigf(acc[1][r] + bf1);
        float gv = tanhf_(acc[2][r] + bg1);
        float ov = sigf(acc[3][r] + bo1);
        float cn = fv * c1r[r] + iv * gv;
        c1r[r] = cn;
        tb[((l >> 4) * 4 + r) * 16 + lr] = f2bf(ov * tanhf_(cn));
      }
      asm volatile("s_waitcnt lgkmcnt(0)" ::: "memory");
      __builtin_amdgcn_sched_barrier(0);
      bf8 hv1 = *(const bf8*)(tb + row2 * 16 + ch2 * 4);
      s4 sv = { hv1[0], hv1[1], hv1[2], hv1[3] };
      GST2(h1wp + strow, sv);
      publish(h1f, mem, (unsigned)(ph + 1));
    }

    // ---- head[ph-2] (rotating member), uses h1C regs ----
    if (ph >= 2 && ((ph - 2) & 15) == mem) {
      const int th = ph - 2;
      f32x4 ac0 = {0,0,0,0}, ac1 = {0,0,0,0};
#pragma unroll
      for (int kt = 0; kt < 8; ++kt) {
        bf8 b0 = *(const bf8*)(ldsw + (size_t)(104 + kt) * 512 + l * 8);
        bf8 b1 = *(const bf8*)(ldsw + (size_t)(112 + kt) * 512 + l * 8);
        ac0 = MFMA16(h1C[kt], b0, ac0);
        ac1 = MFMA16(h1C[kt], b1, ac1);
      }
#pragma unroll
      for (int r = 0; r < 4; ++r) {
        int row = r0 + (l >> 4) * 4 + r;
        float v0 = ac0[r] + hb0;
        float v1 = (lr < 4) ? (ac1[r] + hb1) : -1e30f;
        float m = fmaxf(v0, v1);
#pragma unroll
        for (int msk = 1; msk < 16; msk <<= 1) m = fmaxf(m, __shfl_xor(m, msk, 64));
        float s = __expf(v0 - m) + ((lr < 4) ? __expf(v1 - m) : 0.f);
#pragma unroll
        for (int msk = 1; msk < 16; msk <<= 1) s += __shfl_xor(s, msk, 64);
        float lse = m + __logf(s);
        int tok = P.X[row * D_ + th];
        float lt = ((lr == tok) ? v0 : 0.f) + ((lr + 16 == tok) ? v1 : 0.f);
#pragma unroll
        for (int msk = 1; msk < 16; msk <<= 1) lt += __shfl_xor(lt, msk, 64);
        lq[r] += lt - lse;
      }
    }

    // ---- xa for phase ph+1 (plain cached loads; outstanding asm loads ~done) ----
    if (ph + 1 < D_) {
      int tok = P.X[rowA * D_ + ph];
#pragma unroll
      for (int kt = 0; kt < 2; ++kt) {
        int k0 = kt * 32 + lk;
        xaN[kt] = mod_frag(P.embB + tok * E_ + k0, P.gbB + (size_t)rowA * 128 + k0);
      }
    }

    // ---- wait h1 flags, then issue next-phase h1 loads (h1[ph-1]) ----
    if (ph >= 1 && ph <= D_) waitflags(h1f, mem, (unsigned)(ph + 1));
    if (ph <= D_) {
      const unsigned short* pb = h1wp + (size_t)rowA * H_ + lk;
#pragma unroll
      for (int kt = 0; kt < 8; ++kt) GLD(h1N[kt], pb + kt * 32);
    }
  };

  for (int base = 0; base < 258; base += 2) {
    body(base,     haA, haB, h1A, h1B, xaA, xaB);
    body(base + 1, haB, haA, h1B, h1A, xaB, xaA);
  }

  // ---- merge per-member head partials ----
#pragma unroll
  for (int r = 0; r < 4; ++r) {
    int row = r0 + (l >> 4) * 4 + r;
    if (lr == 0) atomicAdd(&P.out[row], lq[r]);
  }
}

// ---------------------------------------------------------------------------
extern "C" void kernel_launch(void* const* d_in, const int* in_sizes, int n_in,
                              void* d_out, int out_size, void* d_ws, size_t ws_size,
                              hipStream_t stream)
{
  (void)in_sizes; (void)n_in; (void)ws_size;
  const float* U    = (const float*)d_in[0];
  const int*   X    = (const int*)  d_in[1];
  const float* emb  = (const float*)d_in[2];
  const float* u0w  = (const float*)d_in[3];
  const float* u0b  = (const float*)d_in[4];
  const float* gw1  = (const float*)d_in[5];
  const float* gb1  = (const float*)d_in[6];
  const float* glnw = (const float*)d_in[7];
  const float* glnb = (const float*)d_in[8];
  const float* gw2  = (const float*)d_in[9];
  const float* gb2  = (const float*)d_in[10];
  const float* bw1  = (const float*)d_in[11];
  const float* bb1  = (const float*)d_in[12];
  const float* blnw = (const float*)d_in[13];
  const float* blnb = (const float*)d_in[14];
  const float* bw2  = (const float*)d_in[15];
  const float* bb2  = (const float*)d_in[16];
  const float* wih0 = (const float*)d_in[17];
  const float* whh0 = (const float*)d_in[18];
  const float* bih0 = (const float*)d_in[19];
  const float* bhh0 = (const float*)d_in[20];
  const float* wih1 = (const float*)d_in[21];
  const float* whh1 = (const float*)d_in[22];
  const float* bih1 = (const float*)d_in[23];
  const float* bhh1 = (const float*)d_in[24];
  const float* headw = (const float*)d_in[25];
  const float* headb = (const float*)d_in[26];
  float* out = (float*)d_out;

  char* ws = (char*)d_ws;
  size_t off = 0;
  auto alloc = [&](size_t bytes) -> void* {
    void* p = ws + off; off += (bytes + 255) & ~(size_t)255; return p;
  };
  unsigned short* W0p  = (unsigned short*)alloc((size_t)1024 * 320 * 2);
  unsigned short* W1p  = (unsigned short*)alloc((size_t)1024 * 512 * 2);
  unsigned short* Wg1p = (unsigned short*)alloc((size_t)512 * 512 * 2);
  unsigned short* Wb1p = (unsigned short*)alloc((size_t)512 * 512 * 2);
  unsigned short* Wg2p = (unsigned short*)alloc((size_t)64 * 512 * 2);
  unsigned short* Wb2p = (unsigned short*)alloc((size_t)64 * 512 * 2);
  unsigned short* Wu0p = (unsigned short*)alloc((size_t)64 * 512 * 2);
  unsigned short* Whp  = (unsigned short*)alloc((size_t)32 * 256 * 2);
  unsigned short* Ubf  = (unsigned short*)alloc((size_t)B_ * UD_ * 2);
  float*          Hgb  = (float*)alloc((size_t)B_ * 1024 * 4);
  unsigned short* Hsi  = (unsigned short*)alloc((size_t)B_ * 1024 * 2);
  float*          GamBet = (float*)alloc((size_t)B_ * 128 * 4);
  unsigned short* GamBetB = (unsigned short*)alloc((size_t)B_ * 128 * 2);
  unsigned short* embB = (unsigned short*)alloc((size_t)K_ * E_ * 2);
  unsigned short* E0   = (unsigned short*)alloc((size_t)B_ * E_ * 2);
  size_t zoff = off;
  unsigned short* H0   = (unsigned short*)alloc((size_t)2 * B_ * H_ * 2);
  unsigned short* H1   = (unsigned short*)alloc((size_t)2 * B_ * H_ * 2);
  unsigned*       flags = (unsigned*)alloc((size_t)2 * 16 * 16 * sizeof(unsigned));
  size_t zbytes = off - zoff;

  hipMemsetAsync(ws + zoff, 0, zbytes, stream);
  hipMemsetAsync(out, 0, (size_t)out_size * sizeof(float), stream);

  auto pg = [](int tot) { return dim3((tot + 255) / 256); };
  pack_w<<<pg(64 * 2 * 64),  256, 0, stream>>>(wih0, W0p,  64,  2, 10, 0,  64, 1024);
  pack_w<<<pg(64 * 8 * 64),  256, 0, stream>>>(whh0, W0p,  64,  8, 10, 2, 256, 1024);
  pack_w<<<pg(64 * 8 * 64),  256, 0, stream>>>(wih1, W1p,  64,  8, 16, 0, 256, 1024);
  pack_w<<<pg(64 * 8 * 64),  256, 0, stream>>>(whh1, W1p,  64,  8, 16, 8, 256, 1024);
  pack_w<<<pg(32 * 16 * 64), 256, 0, stream>>>(gw1,  Wg1p, 32, 16, 16, 0, 512, 512);
  pack_w<<<pg(32 * 16 * 64), 256, 0, stream>>>(bw1,  Wb1p, 32, 16, 16, 0, 512, 512);
  pack_w<<<pg(4 * 16 * 64),  256, 0, stream>>>(gw2,  Wg2p,  4, 16, 16, 0, 512, 64);
  pack_w<<<pg(4 * 16 * 64),  256, 0, stream>>>(bw2,  Wb2p,  4, 16, 16, 0, 512, 64);
  pack_w<<<pg(4 * 16 * 64),  256, 0, stream>>>(u0w,  Wu0p,  4, 16, 16, 0, 512, 64);
  pack_w<<<pg(2 * 8 * 64),   256, 0, stream>>>(headw, Whp,  2,  8,  8, 0, 256, 20);
  cvt_bf<<<pg(B_ * UD_ / 8), 256, 0, stream>>>(U, Ubf, B_ * UD_ / 8);
  cvt_bf<<<pg(K_ * E_ / 8),  256, 0, stream>>>(emb, embB, K_ * E_ / 8);

  gemm_bt<false><<<dim3(8, 32), 256, 0, stream>>>(Ubf, UD_, 0, Wg1p, 16, Hgb, 1024, 0,   gb1);
  gemm_bt<false><<<dim3(8, 32), 256, 0, stream>>>(Ubf, UD_, 0, Wb1p, 16, Hgb, 1024, 512, bb1);
  ln_silu<<<1024, 256, 0, stream>>>(Hgb, Hsi, glnw, glnb, blnw, blnb);
  gemm_bt<false><<<dim3(1, 32), 256, 0, stream>>>(Hsi, 1024, 0,   Wg2p, 16, GamBet, 128, 0,  gb2);
  gemm_bt<false><<<dim3(1, 32), 256, 0, stream>>>(Hsi, 1024, 512, Wb2p, 16, GamBet, 128, 64, bb2);
  cvt_bf<<<pg(B_ * 128 / 8), 256, 0, stream>>>(GamBet, GamBetB, B_ * 128 / 8);
  gemm_bt<true><<<dim3(1, 32), 256, 0, stream>>>(Ubf, UD_, 0, Wu0p, 16, E0, E_, 0, u0b);

  PParams P;
  P.embB = embB; P.gbB = GamBetB; P.E0 = E0;
  P.W0p = W0p; P.W1p = W1p; P.Whp = Whp;
  P.H0 = H0; P.H1 = H1; P.flags = flags;
  P.bih0 = bih0; P.bhh0 = bhh0; P.bih1 = bih1; P.bhh1 = bhh1;
  P.headb = headb; P.X = X; P.out = out;
  persistent<<<dim3(256), dim3(512), 0, stream>>>(P);
}

// Round 9
// 2602.868 us; speedup vs baseline: 1.3661x; 1.3661x over previous
//
#include <hip/hip_runtime.h>

// Problem dims
#define B_   2048
#define D_   256
#define K_   20
#define UD_  512
#define E_   64
#define H_   256
#define HID_ 512

typedef __attribute__((ext_vector_type(8))) short bf8;    // 8 x bf16 MFMA A/B frag
typedef __attribute__((ext_vector_type(4))) short s4;     // 4 x bf16 (8B)
typedef __attribute__((ext_vector_type(4))) float f32x4;  // MFMA C/D frag
typedef __attribute__((ext_vector_type(4))) float f4;

#define MFMA16(a,b,c) __builtin_amdgcn_mfma_f32_16x16x32_bf16(a, b, c, 0, 0, 0)

// Device-coherent (LLC-point) accesses via sc1 -> no cache flush/inv.
#define GLD(dst, p)  asm volatile("global_load_dwordx4 %0, %1, off sc1" : "=v"(dst) : "v"(p))
#define GST2(p, v)   asm volatile("global_store_dwordx2 %0, %1, off sc1" :: "v"(p), "v"(v) : "memory")
#define GSTD(p, v)   asm volatile("global_store_dword %0, %1, off sc1" :: "v"(p), "v"(v) : "memory")
#define GLDD(dst, p) asm volatile("global_load_dword %0, %1, off sc1\n\ts_waitcnt vmcnt(0)" : "=v"(dst) : "v"(p) : "memory")

__device__ __forceinline__ unsigned short f2bf(float x) {
  unsigned u = __float_as_uint(x);
  u += 0x7fffu + ((u >> 16) & 1u);   // RNE
  return (unsigned short)(u >> 16);
}
__device__ __forceinline__ float bfu(unsigned short x) {
  return __uint_as_float(((unsigned)x) << 16);
}
__device__ __forceinline__ float sigf(float x) {
  return __builtin_amdgcn_rcpf(1.0f + __expf(-x));
}
__device__ __forceinline__ float tanhf_(float x) {
  return 1.0f - 2.0f * __builtin_amdgcn_rcpf(__expf(2.0f * x) + 1.0f);
}

// ---------------------------------------------------------------------------
// Pack a [N,K] row-major f32 weight into MFMA B-fragment order (bf16).
// ---------------------------------------------------------------------------
__global__ __launch_bounds__(256) void pack_w(const float* __restrict__ W,
    unsigned short* __restrict__ dst, int NT, int KTsrc, int KTtot, int kt0,
    int ldw, int Nsrc)
{
  int idx = blockIdx.x * 256 + threadIdx.x;
  int total = NT * KTsrc * 64;
  if (idx >= total) return;
  int l  = idx & 63;
  int fk = idx >> 6;
  int kt = fk % KTsrc;
  int nt = fk / KTsrc;
  int n = nt * 16 + (l & 15);
  int k = kt * 32 + ((l >> 4) * 8);
  bf8 o;
#pragma unroll
  for (int j = 0; j < 8; ++j)
    o[j] = (n < Nsrc) ? (short)f2bf(W[(size_t)n * ldw + k + j]) : (short)0;
  *(bf8*)(dst + (((size_t)(nt * KTtot + kt0 + kt)) * 64 + l) * 8) = o;
}

// f32 -> bf16 row-major convert (8 elems / thread)
__global__ __launch_bounds__(256) void cvt_bf(const float* __restrict__ src,
    unsigned short* __restrict__ dst, int n8)
{
  int i = blockIdx.x * 256 + threadIdx.x;
  if (i >= n8) return;
  const f4* s = (const f4*)(src + (size_t)i * 8);
  f4 v0 = s[0], v1 = s[1];
  bf8 o;
#pragma unroll
  for (int j = 0; j < 4; ++j) { o[j] = (short)f2bf(v0[j]); o[4 + j] = (short)f2bf(v1[j]); }
  *(bf8*)(dst + (size_t)i * 8) = o;
}

// ---------------------------------------------------------------------------
// Generic C = A @ W^T + bias (pre-pass FiLM GEMMs).
// ---------------------------------------------------------------------------
template<bool OUTBF>
__global__ __launch_bounds__(256) void gemm_bt(
    const unsigned short* __restrict__ A, int lda, int aoff,
    const unsigned short* __restrict__ Bp, int KT,
    void* __restrict__ Cptr, int ldc, int coff,
    const float* __restrict__ bias)
{
  int tid = threadIdx.x;
  int l = tid & 63, w = tid >> 6;
  int wr = w >> 1, wc = w & 1;
  int r0 = blockIdx.y * 64 + wr * 32;
  int n0 = blockIdx.x * 64 + wc * 32;
  int lr = l & 15, lk = (l >> 4) * 8;
  f32x4 acc[2][2] = {};
  const unsigned short* a0p = A + (size_t)(r0 + lr) * lda + aoff + lk;
  const unsigned short* a1p = A + (size_t)(r0 + 16 + lr) * lda + aoff + lk;
  int ntb = n0 >> 4;
  for (int kt = 0; kt < KT; ++kt) {
    bf8 a0 = *(const bf8*)(a0p + kt * 32);
    bf8 a1 = *(const bf8*)(a1p + kt * 32);
    bf8 b0 = *(const bf8*)(Bp + (((size_t)(ntb + 0) * KT + kt) * 64 + l) * 8);
    bf8 b1 = *(const bf8*)(Bp + (((size_t)(ntb + 1) * KT + kt) * 64 + l) * 8);
    acc[0][0] = MFMA16(a0, b0, acc[0][0]);
    acc[0][1] = MFMA16(a0, b1, acc[0][1]);
    acc[1][0] = MFMA16(a1, b0, acc[1][0]);
    acc[1][1] = MFMA16(a1, b1, acc[1][1]);
  }
#pragma unroll
  for (int mi = 0; mi < 2; ++mi)
#pragma unroll
  for (int nj = 0; nj < 2; ++nj)
#pragma unroll
  for (int r = 0; r < 4; ++r) {
    int row = r0 + mi * 16 + (l >> 4) * 4 + r;
    int n = n0 + nj * 16 + lr;
    float v = acc[mi][nj][r] + bias[n];
    if (OUTBF) ((unsigned short*)Cptr)[(size_t)row * ldc + coff + n] = f2bf(v);
    else       ((float*)Cptr)[(size_t)row * ldc + coff + n] = v;
  }
}

// LayerNorm(512) + SiLU over Hgb [2048,1024].
__global__ __launch_bounds__(256) void ln_silu(
    const float* __restrict__ Hgb, unsigned short* __restrict__ Hsi,
    const float* __restrict__ gw, const float* __restrict__ gb,
    const float* __restrict__ bw, const float* __restrict__ bb)
{
  int tid = threadIdx.x;
  int l = tid & 63, w = tid >> 6;
  int gwv = blockIdx.x * 4 + w;
  int row = gwv >> 1, br = gwv & 1;
  const float* base = Hgb + (size_t)row * 1024 + br * 512 + l * 8;
  f4 v0 = *(const f4*)base;
  f4 v1 = *(const f4*)(base + 4);
  float s1 = 0.f, s2 = 0.f;
#pragma unroll
  for (int j = 0; j < 4; ++j) { s1 += v0[j] + v1[j]; s2 += v0[j] * v0[j] + v1[j] * v1[j]; }
  for (int m = 1; m < 64; m <<= 1) { s1 += __shfl_xor(s1, m, 64); s2 += __shfl_xor(s2, m, 64); }
  float mean = s1 * (1.0f / 512.0f);
  float var  = s2 * (1.0f / 512.0f) - mean * mean;
  float rstd = rsqrtf(var + 1e-5f);
  const float* W  = br ? bw : gw;
  const float* Bb = br ? bb : gb;
  bf8 o;
#pragma unroll
  for (int j = 0; j < 8; ++j) {
    float x = (j < 4) ? v0[j] : v1[j - 4];
    float y = (x - mean) * rstd * W[l * 8 + j] + Bb[l * 8 + j];
    o[j] = (short)f2bf(y * sigf(y));
  }
  *(bf8*)(Hsi + (size_t)row * 1024 + br * 512 + l * 8) = o;
}

// ---------------------------------------------------------------------------
// Persistent kernel, v7: wave-decoupled flags.
// 16 groups (128 rows) x 16 members (16 h-cols); 512-thread blocks (8 waves,
// 2/SIMD), each wave owns ONE 16-row M-tile. Rows are partitioned by wave
// index, so wave w of member m exchanges data ONLY with wave w of the other
// 15 members -> per-(group,wave) flag lines; NO __syncthreads in the loop.
// Per wave per phase: issue loads -> L0 -> store h0 -> L1 -> store h1 ->
// publish own flag (vmcnt(0), own stores only) -> head (old h1a regs) ->
// xa[ph+1] -> poll 15 peer flags. Poll stalls hide under the co-resident
// wave on the same SIMD.
// ---------------------------------------------------------------------------
struct PParams {
  const unsigned short* embB;
  const unsigned short* gbB;
  const unsigned short* E0;
  const unsigned short* W0p;
  const unsigned short* W1p;
  const unsigned short* Whp;
  unsigned short* H0;
  unsigned short* H1;
  unsigned* flags;               // [16 gid][8 wave][16 mem] u32 = 64B line each
  const float* bih0; const float* bhh0;
  const float* bih1; const float* bhh1;
  const float* headb;
  const int* X;
  float* out;
};

__device__ __forceinline__ bf8 mod_frag(const unsigned short* e,
                                        const unsigned short* gb)
{
  bf8 ev = *(const bf8*)e;
  bf8 gv = *(const bf8*)gb;
  bf8 bv = *(const bf8*)(gb + 64);
  bf8 o;
#pragma unroll
  for (int j = 0; j < 8; ++j) {
    float x = bfu((unsigned short)ev[j]) * (1.0f + bfu((unsigned short)gv[j]))
            + bfu((unsigned short)bv[j]);
    o[j] = (short)f2bf(x);
  }
  return o;
}

// per-wave publish: wait own vmem (stores) done, then 1-lane flag store
__device__ __forceinline__ void publish_wave(unsigned* wf, int mem, int lane,
                                             unsigned target)
{
  asm volatile("s_waitcnt vmcnt(0)" ::: "memory");
  __builtin_amdgcn_sched_barrier(0);
  if (lane == 0) GSTD(&wf[mem], target);
}
// per-wave wait: 15 lanes poll the (gid,wave) 64B flag line
__device__ __forceinline__ void wait_wave(unsigned* wf, int mem, int lane,
                                          unsigned target)
{
  if (lane < 16 && lane != mem) {
    const unsigned* fp = &wf[lane];
    unsigned v;
    GLDD(v, fp);
    while (v < target) {
      __builtin_amdgcn_s_sleep(1);
      GLDD(v, fp);
    }
  }
}

__global__ __launch_bounds__(512, 2) void persistent(PParams P)
{
  __shared__ __align__(16) unsigned short ldsw[120 * 512];  // 120 KB weights
  __shared__ __align__(16) unsigned short tps[8][256];      // 4 KB transpose
  const int tid = threadIdx.x;
  const int l = tid & 63, w = tid >> 6;          // w in 0..7
  const int lr = l & 15, lk = (l >> 4) * 8;
  const int bx = blockIdx.x;
  const int gid = bx & 15;
  const int mem = bx >> 4;
  unsigned* wf = P.flags + ((size_t)(gid * 8 + w)) * 16;   // this wave's line

  // ---- stage weight slices into LDS ----
  for (int f = w; f < 104; f += 8) {
    const unsigned short* src;
    if (f < 40) {
      int g = f / 10, kt = f - g * 10;
      src = P.W0p + (((size_t)((g * 16 + mem) * 10 + kt)) * 64 + l) * 8;
    } else {
      int f1 = f - 40; int g = f1 >> 4, kt = f1 & 15;
      src = P.W1p + (((size_t)((g * 16 + mem) * 16 + kt)) * 64 + l) * 8;
    }
    *(bf8*)(ldsw + (size_t)f * 512 + l * 8) = *(const bf8*)src;
  }
  for (int f = w; f < 16; f += 8)
    *(bf8*)(ldsw + (size_t)(104 + f) * 512 + l * 8) =
        *(const bf8*)(P.Whp + ((size_t)f * 64 + l) * 8);
  __syncthreads();   // the ONLY block-wide sync; ldsw is read-only afterwards

  const int r0 = gid * 128 + w * 16;             // this wave's 16 rows
  const int c  = mem * 16 + lr;
  const size_t HN = (size_t)B_ * H_;
  const int rowA = r0 + lr;
  const int row2 = l & 15, ch2 = (l >> 4) & 3;
  const size_t strow = (size_t)(r0 + row2) * H_ + mem * 16 + ch2 * 4;
  unsigned short* tb = &tps[w][0];

  const float bi0 = P.bih0[c]           + P.bhh0[c];
  const float bf0 = P.bih0[H_ + c]      + P.bhh0[H_ + c];
  const float bg0 = P.bih0[2 * H_ + c]  + P.bhh0[2 * H_ + c];
  const float bo0 = P.bih0[3 * H_ + c]  + P.bhh0[3 * H_ + c];
  const float bi1 = P.bih1[c]           + P.bhh1[c];
  const float bf1 = P.bih1[H_ + c]      + P.bhh1[H_ + c];
  const float bg1 = P.bih1[2 * H_ + c]  + P.bhh1[2 * H_ + c];
  const float bo1 = P.bih1[3 * H_ + c]  + P.bhh1[3 * H_ + c];
  const float hb0 = P.headb[lr];
  const float hb1 = (lr < 4) ? P.headb[16 + lr] : 0.f;

  float c0r[4] = {};
  float c1r[4] = {};
  float lq[4]  = {};

  // xa for phase 0
  bf8 xa[2];
#pragma unroll
  for (int kt = 0; kt < 2; ++kt)
    xa[kt] = *(const bf8*)(P.E0 + (size_t)rowA * E_ + kt * 32 + lk);

  for (int ph = 0; ph <= 257; ++ph) {
    const unsigned short* h0r = P.H0 + ((size_t)((ph + 1) & 1)) * HN; // h0[ph-1]
    unsigned short*       h0wp = P.H0 + ((size_t)(ph & 1)) * HN;      // h0[ph]
    const unsigned short* h1r = P.H1 + ((size_t)(ph & 1)) * HN;       // h1[ph-2]
    unsigned short*       h1wp = P.H1 + ((size_t)((ph + 1) & 1)) * HN;// h1[ph-1]

    // ---- issue A-fragment loads: ha (oldest 8), then h1a ----
    bf8 ha[8], h1a[8];
    {
      const unsigned short* pa = h0r + (size_t)rowA * H_ + lk;
#pragma unroll
      for (int kt = 0; kt < 8; ++kt) GLD(ha[kt], pa + kt * 32);
      const unsigned short* pb = h1r + (size_t)rowA * H_ + lk;
#pragma unroll
      for (int kt = 0; kt < 8; ++kt) GLD(h1a[kt], pb + kt * 32);
    }

    // ---- L0[ph]: kt0-1 on xa while ha is in flight ----
    f32x4 acc0[4] = {};
    if (ph < D_) {
#pragma unroll
      for (int kt = 0; kt < 2; ++kt)
#pragma unroll
      for (int g = 0; g < 4; ++g) {
        bf8 b = *(const bf8*)(ldsw + (size_t)(g * 10 + kt) * 512 + l * 8);
        acc0[g] = MFMA16(xa[kt], b, acc0[g]);
      }
    }
    asm volatile("s_waitcnt vmcnt(8)" ::: "memory");   // ha resident
    __builtin_amdgcn_sched_barrier(0x100);             // DS reads may cross

    if (ph < D_) {
#pragma unroll
      for (int kt = 2; kt < 10; ++kt)
#pragma unroll
      for (int g = 0; g < 4; ++g) {
        bf8 b = *(const bf8*)(ldsw + (size_t)(g * 10 + kt) * 512 + l * 8);
        acc0[g] = MFMA16(ha[kt - 2], b, acc0[g]);
      }
#pragma unroll
      for (int r = 0; r < 4; ++r) {
        float iv = sigf(acc0[0][r] + bi0);
        float fv = sigf(acc0[1][r] + bf0);
        float gv = tanhf_(acc0[2][r] + bg0);
        float ov = sigf(acc0[3][r] + bo0);
        float cn = fv * c0r[r] + iv * gv;
        c0r[r] = cn;
        tb[((l >> 4) * 4 + r) * 16 + lr] = f2bf(ov * tanhf_(cn));
      }
    }
    asm volatile("s_waitcnt vmcnt(0)" ::: "memory");   // h1a resident
    __builtin_amdgcn_sched_barrier(0x100);
    if (ph < D_) {
      asm volatile("s_waitcnt lgkmcnt(0)" ::: "memory");
      __builtin_amdgcn_sched_barrier(0);
      bf8 hv0 = *(const bf8*)(tb + row2 * 16 + ch2 * 4);
      s4 sv = { hv0[0], hv0[1], hv0[2], hv0[3] };
      GST2(h0wp + strow, sv);
    }

    // ---- L1[ph-1] ----
    if (ph >= 1 && ph <= 256) {
      f32x4 acc[4] = {};
#pragma unroll
      for (int kt = 0; kt < 16; ++kt) {
        bf8 a = (kt < 8) ? ha[kt] : h1a[kt - 8];
#pragma unroll
        for (int g = 0; g < 4; ++g) {
          bf8 b = *(const bf8*)(ldsw + (size_t)(40 + g * 16 + kt) * 512 + l * 8);
          acc[g] = MFMA16(a, b, acc[g]);
        }
      }
#pragma unroll
      for (int r = 0; r < 4; ++r) {
        float iv = sigf(acc[0][r] + bi1);
        float fv = sigf(acc[1][r] + bf1);
        float gv = tanhf_(acc[2][r] + bg1);
        float ov = sigf(acc[3][r] + bo1);
        float cn = fv * c1r[r] + iv * gv;
        c1r[r] = cn;
        tb[((l >> 4) * 4 + r) * 16 + lr] = f2bf(ov * tanhf_(cn));
      }
      asm volatile("s_waitcnt lgkmcnt(0)" ::: "memory");
      __builtin_amdgcn_sched_barrier(0);
      bf8 hv1 = *(const bf8*)(tb + row2 * 16 + ch2 * 4);
      s4 sv = { hv1[0], hv1[1], hv1[2], hv1[3] };
      GST2(h1wp + strow, sv);
    }

    // ---- publish own flag (covers h0[ph] + h1[ph-1]) ----
    if (ph < 257) publish_wave(wf, mem, l, (unsigned)(ph + 1));

    // ---- head[ph-2] (rotating member), uses h1a regs = h1[ph-2] ----
    if (ph >= 2 && ((ph - 2) & 15) == mem) {
      const int th = ph - 2;
      f32x4 ac0 = {0,0,0,0}, ac1 = {0,0,0,0};
#pragma unroll
      for (int kt = 0; kt < 8; ++kt) {
        bf8 b0 = *(const bf8*)(ldsw + (size_t)(104 + kt) * 512 + l * 8);
        bf8 b1 = *(const bf8*)(ldsw + (size_t)(112 + kt) * 512 + l * 8);
        ac0 = MFMA16(h1a[kt], b0, ac0);
        ac1 = MFMA16(h1a[kt], b1, ac1);
      }
#pragma unroll
      for (int r = 0; r < 4; ++r) {
        int row = r0 + (l >> 4) * 4 + r;
        float v0 = ac0[r] + hb0;
        float v1 = (lr < 4) ? (ac1[r] + hb1) : -1e30f;
        float m = fmaxf(v0, v1);
#pragma unroll
        for (int msk = 1; msk < 16; msk <<= 1) m = fmaxf(m, __shfl_xor(m, msk, 64));
        float s = __expf(v0 - m) + ((lr < 4) ? __expf(v1 - m) : 0.f);
#pragma unroll
        for (int msk = 1; msk < 16; msk <<= 1) s += __shfl_xor(s, msk, 64);
        float lse = m + __logf(s);
        int tok = P.X[row * D_ + th];
        float lt = ((lr == tok) ? v0 : 0.f) + ((lr + 16 == tok) ? v1 : 0.f);
#pragma unroll
        for (int msk = 1; msk < 16; msk <<= 1) lt += __shfl_xor(lt, msk, 64);
        lq[r] += lt - lse;
      }
    }

    // ---- xa for phase ph+1 (plain cached loads; fills detect window) ----
    if (ph + 1 < D_) {
      int tok = P.X[rowA * D_ + ph];
#pragma unroll
      for (int kt = 0; kt < 2; ++kt) {
        int k0 = kt * 32 + lk;
        xa[kt] = mod_frag(P.embB + tok * E_ + k0, P.gbB + (size_t)rowA * 128 + k0);
      }
    }

    // ---- wait for wave-w peers ----
    if (ph < 257) wait_wave(wf, mem, l, (unsigned)(ph + 1));
  }

  // ---- merge per-member head partials ----
#pragma unroll
  for (int r = 0; r < 4; ++r) {
    int row = r0 + (l >> 4) * 4 + r;
    if (lr == 0) atomicAdd(&P.out[row], lq[r]);
  }
}

// ---------------------------------------------------------------------------
extern "C" void kernel_launch(void* const* d_in, const int* in_sizes, int n_in,
                              void* d_out, int out_size, void* d_ws, size_t ws_size,
                              hipStream_t stream)
{
  (void)in_sizes; (void)n_in; (void)ws_size;
  const float* U    = (const float*)d_in[0];
  const int*   X    = (const int*)  d_in[1];
  const float* emb  = (const float*)d_in[2];
  const float* u0w  = (const float*)d_in[3];
  const float* u0b  = (const float*)d_in[4];
  const float* gw1  = (const float*)d_in[5];
  const float* gb1  = (const float*)d_in[6];
  const float* glnw = (const float*)d_in[7];
  const float* glnb = (const float*)d_in[8];
  const float* gw2  = (const float*)d_in[9];
  const float* gb2  = (const float*)d_in[10];
  const float* bw1  = (const float*)d_in[11];
  const float* bb1  = (const float*)d_in[12];
  const float* blnw = (const float*)d_in[13];
  const float* blnb = (const float*)d_in[14];
  const float* bw2  = (const float*)d_in[15];
  const float* bb2  = (const float*)d_in[16];
  const float* wih0 = (const float*)d_in[17];
  const float* whh0 = (const float*)d_in[18];
  const float* bih0 = (const float*)d_in[19];
  const float* bhh0 = (const float*)d_in[20];
  const float* wih1 = (const float*)d_in[21];
  const float* whh1 = (const float*)d_in[22];
  const float* bih1 = (const float*)d_in[23];
  const float* bhh1 = (const float*)d_in[24];
  const float* headw = (const float*)d_in[25];
  const float* headb = (const float*)d_in[26];
  float* out = (float*)d_out;

  char* ws = (char*)d_ws;
  size_t off = 0;
  auto alloc = [&](size_t bytes) -> void* {
    void* p = ws + off; off += (bytes + 255) & ~(size_t)255; return p;
  };
  unsigned short* W0p  = (unsigned short*)alloc((size_t)1024 * 320 * 2);
  unsigned short* W1p  = (unsigned short*)alloc((size_t)1024 * 512 * 2);
  unsigned short* Wg1p = (unsigned short*)alloc((size_t)512 * 512 * 2);
  unsigned short* Wb1p = (unsigned short*)alloc((size_t)512 * 512 * 2);
  unsigned short* Wg2p = (unsigned short*)alloc((size_t)64 * 512 * 2);
  unsigned short* Wb2p = (unsigned short*)alloc((size_t)64 * 512 * 2);
  unsigned short* Wu0p = (unsigned short*)alloc((size_t)64 * 512 * 2);
  unsigned short* Whp  = (unsigned short*)alloc((size_t)32 * 256 * 2);
  unsigned short* Ubf  = (unsigned short*)alloc((size_t)B_ * UD_ * 2);
  float*          Hgb  = (float*)alloc((size_t)B_ * 1024 * 4);
  unsigned short* Hsi  = (unsigned short*)alloc((size_t)B_ * 1024 * 2);
  float*          GamBet = (float*)alloc((size_t)B_ * 128 * 4);
  unsigned short* GamBetB = (unsigned short*)alloc((size_t)B_ * 128 * 2);
  unsigned short* embB = (unsigned short*)alloc((size_t)K_ * E_ * 2);
  unsigned short* E0   = (unsigned short*)alloc((size_t)B_ * E_ * 2);
  size_t zoff = off;
  unsigned short* H0   = (unsigned short*)alloc((size_t)2 * B_ * H_ * 2);
  unsigned short* H1   = (unsigned short*)alloc((size_t)2 * B_ * H_ * 2);
  unsigned*       flags = (unsigned*)alloc((size_t)16 * 8 * 16 * sizeof(unsigned));
  size_t zbytes = off - zoff;

  hipMemsetAsync(ws + zoff, 0, zbytes, stream);
  hipMemsetAsync(out, 0, (size_t)out_size * sizeof(float), stream);

  auto pg = [](int tot) { return dim3((tot + 255) / 256); };
  pack_w<<<pg(64 * 2 * 64),  256, 0, stream>>>(wih0, W0p,  64,  2, 10, 0,  64, 1024);
  pack_w<<<pg(64 * 8 * 64),  256, 0, stream>>>(whh0, W0p,  64,  8, 10, 2, 256, 1024);
  pack_w<<<pg(64 * 8 * 64),  256, 0, stream>>>(wih1, W1p,  64,  8, 16, 0, 256, 1024);
  pack_w<<<pg(64 * 8 * 64),  256, 0, stream>>>(whh1, W1p,  64,  8, 16, 8, 256, 1024);
  pack_w<<<pg(32 * 16 * 64), 256, 0, stream>>>(gw1,  Wg1p, 32, 16, 16, 0, 512, 512);
  pack_w<<<pg(32 * 16 * 64), 256, 0, stream>>>(bw1,  Wb1p, 32, 16, 16, 0, 512, 512);
  pack_w<<<pg(4 * 16 * 64),  256, 0, stream>>>(gw2,  Wg2p,  4, 16, 16, 0, 512, 64);
  pack_w<<<pg(4 * 16 * 64),  256, 0, stream>>>(bw2,  Wb2p,  4, 16, 16, 0, 512, 64);
  pack_w<<<pg(4 * 16 * 64),  256, 0, stream>>>(u0w,  Wu0p,  4, 16, 16, 0, 512, 64);
  pack_w<<<pg(2 * 8 * 64),   256, 0, stream>>>(headw, Whp,  2,  8,  8, 0, 256, 20);
  cvt_bf<<<pg(B_ * UD_ / 8), 256, 0, stream>>>(U, Ubf, B_ * UD_ / 8);
  cvt_bf<<<pg(K_ * E_ / 8),  256, 0, stream>>>(emb, embB, K_ * E_ / 8);

  gemm_bt<false><<<dim3(8, 32), 256, 0, stream>>>(Ubf, UD_, 0, Wg1p, 16, Hgb, 1024, 0,   gb1);
  gemm_bt<false><<<dim3(8, 32), 256, 0, stream>>>(Ubf, UD_, 0, Wb1p, 16, Hgb, 1024, 512, bb1);
  ln_silu<<<1024, 256, 0, stream>>>(Hgb, Hsi, glnw, glnb, blnw, blnb);
  gemm_bt<false><<<dim3(1, 32), 256, 0, stream>>>(Hsi, 1024, 0,   Wg2p, 16, GamBet, 128, 0,  gb2);
  gemm_bt<false><<<dim3(1, 32), 256, 0, stream>>>(Hsi, 1024, 512, Wb2p, 16, GamBet, 128, 64, bb2);
  cvt_bf<<<pg(B_ * 128 / 8), 256, 0, stream>>>(GamBet, GamBetB, B_ * 128 / 8);
  gemm_bt<true><<<dim3(1, 32), 256, 0, stream>>>(Ubf, UD_, 0, Wu0p, 16, E0, E_, 0, u0b);

  PParams P;
  P.embB = embB; P.gbB = GamBetB; P.E0 = E0;
  P.W0p = W0p; P.W1p = W1p; P.Whp = Whp;
  P.H0 = H0; P.H1 = H1; P.flags = flags;
  P.bih0 = bih0; P.bhh0 = bhh0; P.bih1 = bih1; P.bhh1 = bhh1;
  P.headb = headb; P.X = X; P.out = out;
  persistent<<<dim3(256), dim3(512), 0, stream>>>(P);
}